// Round 10
// baseline (249.242 us; speedup 1.0000x reference)
//
#include <hip/hip_runtime.h>
#include <math.h>

#define NNODES 50000
#define EORIG  800000
#define ETOT   850000     // EORIG + NNODES self loops
#define NBUCK  196        // ceil(NNODES/256) buckets of 256 nodes (bucket = dst>>8)
#define BSTRIDE 5120      // fixed slots per bucket (mean 4352, +12 sigma headroom)
#define P2CHUNK 4096      // edges per partition block
#define NBLK2  ((ETOT + P2CHUNK - 1)/P2CHUNK)   // 208

typedef __attribute__((ext_vector_type(8))) short bf8_t;   // 8 bf16 (bits in shorts)
typedef __attribute__((ext_vector_type(4))) short bf4_t;   // 4 bf16
typedef __attribute__((ext_vector_type(4))) float f4_t;
typedef __attribute__((ext_vector_type(2))) float f2_t;

constexpr float LOG2E = 1.44269504f;

constexpr size_t align256(size_t x){ return (x + 255) & ~size_t(255); }
constexpr size_t OFF_OFFSETS = 0;                                           // N ints
constexpr size_t OFF_DEG     = OFF_OFFSETS + align256((size_t)NNODES*4);    // N ints
constexpr size_t OFF_GCUR    = OFF_DEG     + align256((size_t)NNODES*4);    // NBUCK ints
constexpr size_t OFF_EPACK   = OFF_GCUR    + align256(NBUCK*4);             // NBUCK*BSTRIDE ints
constexpr size_t OFF_SRC     = OFF_EPACK   + align256((size_t)NBUCK*BSTRIDE*4);
constexpr size_t OFF_AS1     = OFF_SRC     + align256((size_t)NBUCK*BSTRIDE*4); // N*8 f32 ([node][head])
constexpr size_t OFF_AD1     = OFF_AS1     + align256((size_t)NNODES*8*4);
constexpr size_t OFF_W1T     = OFF_AD1     + align256((size_t)NNODES*8*4);  // 256*256 bf16 (n-major)
constexpr size_t OFF_W2T     = OFF_W1T     + align256(256*256*2);           // 64*256 bf16 (n-major)
constexpr size_t OFF_H1F8    = OFF_W2T     + align256(64*256*2);            // N*256 fp8 (node-major)
constexpr size_t OFF_OUT1B   = OFF_H1F8    + align256((size_t)NNODES*256);  // N*256 bf16
// h2b overlays dead h1f8 after aggregate1
constexpr size_t OFF_H2B     = OFF_H1F8;                                    // N*64 bf16
constexpr size_t OFF_AS2     = OFF_OUT1B   + align256((size_t)NNODES*256*2);
constexpr size_t OFF_AD2     = OFF_AS2     + align256((size_t)NNODES*4);

__device__ __forceinline__ unsigned short f2bf(float f){
    union { float f; unsigned u; } v; v.f = f;
    unsigned r = v.u + 0x7FFF + ((v.u >> 16) & 1);   // RNE
    return (unsigned short)(r >> 16);
}
__device__ __forceinline__ float bf2f(unsigned short s){
    union { unsigned u; float f; } v; v.u = ((unsigned)s) << 16;
    return v.f;
}

// ---------------- CSR construction: LDS multisplit, fixed-stride buckets ---

// block-level multisplit into fixed-stride bucket regions
// epack = (src<<8) | (dst & 255);  src < 50000 fits in 24 bits.
__global__ __launch_bounds__(256) void p3_part(const int* __restrict__ ei, int* __restrict__ gcur,
                                               int* __restrict__ epack){
    __shared__ int h[NBUCK];    // block hist -> block base per bucket
    __shared__ int r[NBUCK];    // intra-block rank cursor
    const int t = threadIdx.x;
    for (int i = t; i < NBUCK; i += 256){ h[i] = 0; r[i] = 0; }
    __syncthreads();
    const int base = blockIdx.x * P2CHUNK;
    int srcs[P2CHUNK/256], dsts[P2CHUNK/256];
#pragma unroll
    for (int j = 0; j < P2CHUNK/256; j++){
        int e = base + j*256 + t;
        if (e < ETOT){
            if (e < EORIG){ srcs[j] = ei[e]; dsts[j] = ei[EORIG + e]; }
            else          { srcs[j] = dsts[j] = e - EORIG; }
            atomicAdd(&h[dsts[j] >> 8], 1);
        } else dsts[j] = -1;
    }
    __syncthreads();
    for (int i = t; i < NBUCK; i += 256){
        int c = h[i];
        h[i] = c ? atomicAdd(&gcur[i], c) : 0;
    }
    __syncthreads();
#pragma unroll
    for (int j = 0; j < P2CHUNK/256; j++){
        if (dsts[j] >= 0){
            int b = dsts[j] >> 8;
            int rk = atomicAdd(&r[b], 1);
            epack[h[b] + rk] = (srcs[j] << 8) | (dsts[j] & 255);
        }
    }
}

// one block per bucket -> local CSR in LDS; offsets/deg coalesced;
// srclist writes confined to the bucket's contiguous region.
__global__ __launch_bounds__(256) void p4_csr(const int* __restrict__ gcur, const int* __restrict__ epack,
                                              int* __restrict__ offsets, int* __restrict__ deg_g,
                                              int* __restrict__ srclist){
    __shared__ int deg[256];
    __shared__ int sm[256];
    __shared__ int cur[256];
    const int b = blockIdx.x, t = threadIdx.x;
    const int s0 = b * BSTRIDE, s1 = gcur[b];
    deg[t] = 0; __syncthreads();
    for (int i = s0 + t; i < s1; i += 256) atomicAdd(&deg[epack[i] & 255], 1);
    __syncthreads();
    int v = deg[t];
    sm[t] = v; __syncthreads();
    for (int off = 1; off < 256; off <<= 1){
        int add = (t >= off) ? sm[t-off] : 0;
        __syncthreads();
        sm[t] += add;
        __syncthreads();
    }
    int excl = sm[t] - v;
    int node = (b << 8) + t;
    if (node < NNODES){ offsets[node] = s0 + excl; deg_g[node] = v; }
    cur[t] = s0 + excl;
    __syncthreads();
    for (int i = s0 + t; i < s1; i += 256){
        int p = epack[i];
        int pos = atomicAdd(&cur[p & 255], 1);
        srclist[pos] = p >> 8;
    }
}

// ---------------- weight transpose+convert + gcur init (one launch) --------

__global__ __launch_bounds__(256) void conv_w_k(const float* __restrict__ W1, const float* __restrict__ W2,
                                                short* __restrict__ w1t, short* __restrict__ w2t,
                                                int* __restrict__ gcur){
    int o = blockIdx.x*256 + threadIdx.x;
    if (o < NBUCK) gcur[o] = o * BSTRIDE;
    if (o < 256*256){
        int n = o >> 8, k = o & 255;
        w1t[o] = (short)f2bf(W1[k*256 + n]);
    } else {
        int o2 = o - 256*256;
        if (o2 < 64*256){
            int n = o2 >> 8, k = o2 & 255;
            w2t[o2] = (short)f2bf(W2[k*64 + n]);
        }
    }
}

// ---------------- GEMM1 (MFMA): h1f8 = fp8(x @ W1) ------------------------
// 32x256 tile, 256 threads = 4 waves (wave w -> cols w*64..+63).
// SINGLE barrier + DEEP MLP: stage the whole A tile (8 float4 loads all in
// flight per thread), one __syncthreads, then a fully-unrolled K-loop with a
// 3-deep B register pipeline (12 outstanding B loads per lane). No per-step
// barrier -> no vmcnt(0) drains -> in-flight loads survive across steps.
// Accumulation order identical to the 2-barrier version (s ascending).

__global__ __launch_bounds__(256) void gemm1_mfma(const float* __restrict__ x, const short* __restrict__ w1t,
        const float* __restrict__ a1s, const float* __restrict__ a1d,
        unsigned char* __restrict__ h1f8, float* __restrict__ as1, float* __restrict__ ad1){
    __shared__ short As[32][264];              // 16.5 KB, +8 pad
    const int t = threadIdx.x;                 // 0..255
    const int lane = t & 63, wave = t >> 6;    // 4 waves
    const int quad = lane >> 4, l15 = lane & 15;
    const int r0 = blockIdx.x * 32;
    const int srow = t >> 3;                   // 0..31
    const int sc0  = (t & 7) * 4;              // first col of this thread's chunk
    const bool arow_ok = (r0 + srow) < NNODES;
    const float* xrow = x + (size_t)(r0 + srow)*256 + sc0;
    const float4 fz = {0.f,0.f,0.f,0.f};

    // stage full A tile: 8 coalesced float4 loads/thread (all in flight)
    float4 xa[8];
#pragma unroll
    for (int k=0;k<8;k++)
        xa[k] = arow_ok ? *(const float4*)(xrow + k*32) : fz;
#pragma unroll
    for (int k=0;k<8;k++){
        bf4_t a0;
        a0[0]=f2bf(xa[k].x); a0[1]=f2bf(xa[k].y); a0[2]=f2bf(xa[k].z); a0[3]=f2bf(xa[k].w);
        *(bf4_t*)&As[srow][sc0 + k*32] = a0;
    }
    __syncthreads();                           // the ONLY barrier

    const short* wbase = w1t + (size_t)(wave*64 + l15)*256 + quad*8;
    f4_t zero4 = {0.f,0.f,0.f,0.f};
    f4_t acc[2][4];
#pragma unroll
    for (int i=0;i<2;i++)
#pragma unroll
      for (int j=0;j<4;j++) acc[i][j] = zero4;

    // 3-deep B register pipeline: slots 0..2 hold steps s, s+1, s+2
    bf8_t bq[3][4];
#pragma unroll
    for (int p=0;p<3;p++)
#pragma unroll
      for (int j=0;j<4;j++) bq[p][j] = *(const bf8_t*)(wbase + j*16*256 + p*32);

#pragma unroll
    for (int s = 0; s < 8; s++){
        bf8_t af[2];
#pragma unroll
        for (int i=0;i<2;i++) af[i] = *(const bf8_t*)&As[i*16 + l15][s*32 + quad*8];
#pragma unroll
        for (int i=0;i<2;i++)
#pragma unroll
          for (int j=0;j<4;j++)
            acc[i][j] = __builtin_amdgcn_mfma_f32_16x16x32_bf16(af[i], bq[s%3][j], acc[i][j], 0,0,0);
        if (s + 3 < 8){
            const int kn = (s+3)*32;
#pragma unroll
            for (int j=0;j<4;j++) bq[s%3][j] = *(const bf8_t*)(wbase + j*16*256 + kn);
        }
    }
    // epilogue: fp8 store (HW cvt, node-major) + fused alpha projections (x log2e)
    const int colbase = wave*64;             // this wave's 64 cols = 2 heads
    const int head0 = colbase >> 5;
    float cs[4], cd[4];
#pragma unroll
    for (int j=0;j<4;j++){
        cs[j] = a1s[colbase + j*16 + l15] * LOG2E;
        cd[j] = a1d[colbase + j*16 + l15] * LOG2E;
    }
#pragma unroll
    for (int i=0;i<2;i++){
        int rowb = r0 + i*16 + quad*4;
#pragma unroll
        for (int reg=0; reg<4; reg++){
            int row = rowb + reg;
            bool valid = row < NNODES;
            float sp0=0.f, dp0=0.f, sp1=0.f, dp1=0.f;
#pragma unroll
            for (int j=0;j<4;j++){
                float v = acc[i][j][reg];
                if (j < 2){ sp0 += v*cs[j]; dp0 += v*cd[j]; }
                else      { sp1 += v*cs[j]; dp1 += v*cd[j]; }
                if (valid){
                    unsigned enc = (unsigned)__builtin_amdgcn_cvt_pk_fp8_f32(v, v, 0, false);
                    h1f8[(size_t)row*256 + colbase + j*16 + l15] = (unsigned char)(enc & 0xffu);
                }
            }
            sp0 += __shfl_xor(sp0,1); sp0 += __shfl_xor(sp0,2); sp0 += __shfl_xor(sp0,4); sp0 += __shfl_xor(sp0,8);
            dp0 += __shfl_xor(dp0,1); dp0 += __shfl_xor(dp0,2); dp0 += __shfl_xor(dp0,4); dp0 += __shfl_xor(dp0,8);
            sp1 += __shfl_xor(sp1,1); sp1 += __shfl_xor(sp1,2); sp1 += __shfl_xor(sp1,4); sp1 += __shfl_xor(sp1,8);
            dp1 += __shfl_xor(dp1,1); dp1 += __shfl_xor(dp1,2); dp1 += __shfl_xor(dp1,4); dp1 += __shfl_xor(dp1,8);
            if (valid && l15 == 0){
                as1[row*8 + head0    ] = sp0;
                ad1[row*8 + head0    ] = dp0;
                as1[row*8 + head0 + 1] = sp1;
                ad1[row*8 + head0 + 1] = dp1;
            }
        }
    }
}

// ---------------- GEMM2 (MFMA): h2b = bf16(out1b @ W2), fused as2/ad2 ------
// (round-0 proven version: 128-row tile, 256 threads, LDS-staged A and B)

__global__ __launch_bounds__(256) void gemm2_mfma(const short* __restrict__ ab, const short* __restrict__ w2t,
        const float* __restrict__ a2s, const float* __restrict__ a2d,
        short* __restrict__ h2b, float* __restrict__ as2, float* __restrict__ ad2){
    __shared__ short As[128][40];
    __shared__ short Bs[64][40];
    const int t = threadIdx.x;
    const int lane = t & 63, wave = t >> 6;
    const int quad = lane >> 4, l15 = lane & 15;
    const int r0 = blockIdx.x * 128;
    const int srow = t >> 2, skoff = (t & 3) * 8;
    f4_t zero4 = {0.f,0.f,0.f,0.f};
    f4_t acc[2][4];
#pragma unroll
    for (int i=0;i<2;i++)
#pragma unroll
      for (int j=0;j<4;j++) acc[i][j] = zero4;

    for (int kk = 0; kk < 256; kk += 32){
        bf8_t a0 = {}, a1v = {};
        if (r0 + srow < NNODES)      a0  = *(const bf8_t*)(ab + (size_t)(r0+srow)*256 + kk + skoff);
        if (r0 + srow + 64 < NNODES) a1v = *(const bf8_t*)(ab + (size_t)(r0+srow+64)*256 + kk + skoff);
        bf8_t b0 = *(const bf8_t*)(w2t + (size_t)srow*256 + kk + skoff);   // srow = n (0..63)
        __syncthreads();
        *(bf8_t*)&As[srow   ][skoff] = a0;
        *(bf8_t*)&As[srow+64][skoff] = a1v;
        *(bf8_t*)&Bs[srow   ][skoff] = b0;
        __syncthreads();
        bf8_t af[2], bfr[4];
#pragma unroll
        for (int i=0;i<2;i++) af[i]  = *(const bf8_t*)&As[wave*32 + i*16 + l15][quad*8];
#pragma unroll
        for (int j=0;j<4;j++) bfr[j] = *(const bf8_t*)&Bs[j*16 + l15][quad*8];
#pragma unroll
        for (int i=0;i<2;i++)
#pragma unroll
          for (int j=0;j<4;j++)
            acc[i][j] = __builtin_amdgcn_mfma_f32_16x16x32_bf16(af[i], bfr[j], acc[i][j], 0,0,0);
    }
    float cs[4], cd[4];
#pragma unroll
    for (int j=0;j<4;j++){
        cs[j] = a2s[j*16 + l15] * LOG2E;
        cd[j] = a2d[j*16 + l15] * LOG2E;
    }
#pragma unroll
    for (int i=0;i<2;i++){
        int rowb = r0 + wave*32 + i*16 + quad*4;
#pragma unroll
        for (int reg=0; reg<4; reg++){
            int row = rowb + reg;
            bool valid = row < NNODES;
            float sp=0.f, dp=0.f;
#pragma unroll
            for (int j=0;j<4;j++){
                float v = acc[i][j][reg];
                sp += v*cs[j]; dp += v*cd[j];
                if (valid) h2b[(size_t)row*64 + j*16 + l15] = (short)f2bf(v);
            }
            sp += __shfl_xor(sp,1); sp += __shfl_xor(sp,2); sp += __shfl_xor(sp,4); sp += __shfl_xor(sp,8);
            dp += __shfl_xor(dp,1); dp += __shfl_xor(dp,2); dp += __shfl_xor(dp,4); dp += __shfl_xor(dp,8);
            if (valid && l15 == 0){ as2[row] = sp; ad2[row] = dp; }
        }
    }
}

// ---------------- attention aggregation 1: R0 structure + 2-deep pipeline --
// Per 8-edge group: prefetch group g+1's eight 4B row-slices into registers
// BEFORE accumulating group g, so the serial 8-FMA accumulation chain and
// the p-compute overlap the next group's L2/L3 gather latency (2x MLP).
// Accumulation order per edge unchanged -> bit-identical numerics.

__global__ __launch_bounds__(256) void aggregate1_k(const unsigned char* __restrict__ h1f8,
        const float* __restrict__ as1, const float* __restrict__ ad1,
        const int* __restrict__ offsets, const int* __restrict__ deg_g,
        const int* __restrict__ srclist,
        const float* __restrict__ b1, short* __restrict__ out1b){
    int d = blockIdx.x*4 + (threadIdx.x >> 6);
    int lane = threadIdx.x & 63;
    if (d >= NNODES) return;
    const int head_g = lane >> 3;    // gather phase: lane covers channels head_g*32 + (lane&7)*4 ..
    const int head_p = lane & 7;     // p phase: lane computes p(edge = lane>>3, head = lane&7)
    const int ep     = lane >> 3;
    int start = offsets[d];
    int deg = deg_g[d];
    float ad_p = ad1[d*8 + head_p];
    float denom = 0.f;
    f2_t acc01 = {0.f,0.f}, acc23 = {0.f,0.f};
    for (int w = 0; w < deg; w += 64){
        int deg_w = min(64, deg - w);
        int s_reg = srclist[start + w + min(lane, deg_w-1)];
        int ngr = (deg_w + 7) >> 3;
        // p for group g: edges g*8 .. g*8+7 of this window, all 8 heads
        auto comp_p = [&](int g)->float{
            int ei = g*8 + ep;
            int s  = __shfl(s_reg, min(ei, deg_w-1));
            float e = as1[s*8 + head_p] + ad_p;
            e = fmaxf(0.2f*e, e);
            float p = exp2f(e);
            return (ei < deg_w) ? p : 0.f;
        };
        // gather group g's rows (this lane's 4 channels of each of 8 edges)
        auto fetch = [&](int g, unsigned wv[8]){
#pragma unroll
            for (int e = 0; e < 8; e++){
                int se = __shfl(s_reg, g*8 + e);
                wv[e] = *(const unsigned*)(h1f8 + (size_t)se*256 + lane*4);
            }
        };
        float p_reg = comp_p(0);
        unsigned wv[8];
        fetch(0, wv);
        for (int g = 0; g < ngr; g++){
            float p_cur = p_reg;
            unsigned wn[8];
            if (g + 1 < ngr){
                p_reg = comp_p(g+1);
                fetch(g+1, wn);          // next group's gathers in flight
            }
#pragma unroll
            for (int e = 0; e < 8; e++){
                float pe = __shfl(p_cur, e*8 + head_g);
                f2_t lo = __builtin_amdgcn_cvt_pk_f32_fp8(wv[e], false);
                f2_t hi = __builtin_amdgcn_cvt_pk_f32_fp8(wv[e], true);
                acc01 += pe*lo;
                acc23 += pe*hi;
                denom += pe;
            }
            if (g + 1 < ngr){
#pragma unroll
                for (int e = 0; e < 8; e++) wv[e] = wn[e];
            }
        }
    }
    float inv = 1.f / denom;
    float4 bv = *(const float4*)(b1 + lane*4);
    ushort4 us;
    us.x = f2bf(fmaxf(acc01[0]*inv + bv.x, 0.f));
    us.y = f2bf(fmaxf(acc01[1]*inv + bv.y, 0.f));
    us.z = f2bf(fmaxf(acc23[0]*inv + bv.z, 0.f));
    us.w = f2bf(fmaxf(acc23[1]*inv + bv.w, 0.f));
    *(ushort4*)(out1b + (size_t)d*256 + lane*4) = us;
}

// ---------------- attention aggregation 2: + 2-deep gather pipeline --------
// Same transform as agg1: per 8-edge group, prefetch group g+1's dwordx4
// gather (and its pe/se shuffles) before accumulating group g, overlapping
// the serial 64-FMA accumulation with the next gather's L2/L3 latency.
// Per-edge accumulation order unchanged -> bit-identical numerics.

__global__ __launch_bounds__(256) void aggregate2_k(const unsigned short* __restrict__ h2b,
        const float* __restrict__ as2, const float* __restrict__ ad2,
        const int* __restrict__ offsets, const int* __restrict__ deg_g,
        const int* __restrict__ srclist,
        const float* __restrict__ b2, float* __restrict__ out){
    int d = blockIdx.x*4 + (threadIdx.x >> 6);
    int lane = threadIdx.x & 63;
    if (d >= NNODES) return;
    const int sub = lane >> 3;   // edge slot (0..7)
    const int c8  = lane & 7;    // channels c8*8 .. +7
    int start = offsets[d];
    int deg = deg_g[d];
    float ad_v = ad2[d];
    float denom = 0.f;
    float accv[8] = {0.f,0.f,0.f,0.f,0.f,0.f,0.f,0.f};
    for (int w = 0; w < deg; w += 64){
        int deg_w = min(64, deg - w);
        int s_reg = srclist[start + w + min(lane, deg_w-1)];
        float ev = as2[s_reg] + ad_v;
        ev = fmaxf(0.2f*ev, ev);
        float p_lane = (lane < deg_w) ? exp2f(ev) : 0.f;
        int ngr = (deg_w + 7) >> 3;
        auto fetch = [&](int g, float &pe, bf8_t &hv){
            int eq = g*8 + sub;
            pe = __shfl(p_lane, eq);
            int se = __shfl(s_reg, eq);
            hv = *(const bf8_t*)(h2b + (size_t)se*64 + c8*8);
        };
        float pe_c; bf8_t hv_c;
        fetch(0, pe_c, hv_c);
        for (int g = 0; g < ngr; g++){
            float pe = pe_c; bf8_t hv = hv_c;
            if (g + 1 < ngr) fetch(g+1, pe_c, hv_c);   // next gather in flight
#pragma unroll
            for (int k=0;k<8;k++) accv[k] += pe * bf2f((unsigned short)hv[k]);
            denom += pe;
        }
    }
    // combine the 8 edge-subsets (lane bits 3,4,5)
#pragma unroll
    for (int k=0;k<8;k++){
        accv[k] += __shfl_xor(accv[k], 8);
        accv[k] += __shfl_xor(accv[k], 16);
        accv[k] += __shfl_xor(accv[k], 32);
    }
    denom += __shfl_xor(denom, 8);
    denom += __shfl_xor(denom, 16);
    denom += __shfl_xor(denom, 32);
    float inv = 1.f / denom;
    float v[8];
    float mx = -1e30f;
#pragma unroll
    for (int k=0;k<8;k++){
        v[k] = accv[k]*inv + b2[c8*8 + k];
        mx = fmaxf(mx, v[k]);
    }
    mx = fmaxf(mx, __shfl_xor(mx, 1));
    mx = fmaxf(mx, __shfl_xor(mx, 2));
    mx = fmaxf(mx, __shfl_xor(mx, 4));
    float ss = 0.f;
#pragma unroll
    for (int k=0;k<8;k++) ss += __expf(v[k] - mx);
    ss += __shfl_xor(ss, 1);
    ss += __shfl_xor(ss, 2);
    ss += __shfl_xor(ss, 4);
    if (sub == 0){
        float lg = mx + __logf(ss);
        float4 o0 = {v[0]-lg, v[1]-lg, v[2]-lg, v[3]-lg};
        float4 o1 = {v[4]-lg, v[5]-lg, v[6]-lg, v[7]-lg};
        *(float4*)(out + (size_t)d*64 + c8*8)     = o0;
        *(float4*)(out + (size_t)d*64 + c8*8 + 4) = o1;
    }
}

// ---------------- launch ----------------

extern "C" void kernel_launch(void* const* d_in, const int* in_sizes, int n_in,
                              void* d_out, int out_size, void* d_ws, size_t ws_size,
                              hipStream_t stream){
    const float* x      = (const float*)d_in[0];
    const int*   ei     = (const int*)  d_in[1];
    const float* W1     = (const float*)d_in[2];
    const float* a_src1 = (const float*)d_in[3];
    const float* a_dst1 = (const float*)d_in[4];
    const float* b1     = (const float*)d_in[5];
    const float* W2     = (const float*)d_in[6];
    const float* a_src2 = (const float*)d_in[7];
    const float* a_dst2 = (const float*)d_in[8];
    const float* b2     = (const float*)d_in[9];

    char* ws = (char*)d_ws;
    int*   offsets = (int*)  (ws + OFF_OFFSETS);
    int*   deg_g   = (int*)  (ws + OFF_DEG);
    int*   gcur    = (int*)  (ws + OFF_GCUR);
    int*   epack   = (int*)  (ws + OFF_EPACK);
    int*   srclist = (int*)  (ws + OFF_SRC);
    float* as1     = (float*)(ws + OFF_AS1);
    float* ad1     = (float*)(ws + OFF_AD1);
    short* w1t     = (short*)(ws + OFF_W1T);
    short* w2t     = (short*)(ws + OFF_W2T);
    unsigned char* h1f8 = (unsigned char*)(ws + OFF_H1F8);
    short* out1b   = (short*)(ws + OFF_OUT1B);
    short* h2b     = (short*)(ws + OFF_H2B);
    float* as2     = (float*)(ws + OFF_AS2);
    float* ad2     = (float*)(ws + OFF_AD2);

    // weight prep + gcur init (must precede p3)
    conv_w_k<<<(256*256 + 64*256 + 255)/256, 256, 0, stream>>>(W1, W2, w1t, w2t, gcur);

    // CSR by dst: LDS multisplit with fixed-stride buckets
    p3_part<<<NBLK2, 256, 0, stream>>>(ei, gcur, epack);
    p4_csr <<<NBUCK, 256, 0, stream>>>(gcur, epack, offsets, deg_g, srclist);

    // Layer 1
    gemm1_mfma<<<(NNODES+31)/32, 256, 0, stream>>>(x, w1t, a_src1, a_dst1, h1f8, as1, ad1);
    aggregate1_k<<<(NNODES+3)/4, 256, 0, stream>>>(h1f8, as1, ad1, offsets, deg_g, srclist, b1, out1b);

    // Layer 2
    gemm2_mfma<<<(NNODES+127)/128, 256, 0, stream>>>(out1b, w2t, a_src2, a_dst2, h2b, as2, ad2);
    aggregate2_k<<<(NNODES+3)/4, 256, 0, stream>>>((const unsigned short*)h2b, as2, ad2, offsets, deg_g, srclist, b2, (float*)d_out);
}

// Round 11
// 230.421 us; speedup vs baseline: 1.0817x; 1.0817x over previous
//
#include <hip/hip_runtime.h>
#include <math.h>

#define NNODES 50000
#define EORIG  800000
#define ETOT   850000     // EORIG + NNODES self loops
#define NBUCK  196        // ceil(NNODES/256) buckets of 256 nodes (bucket = dst>>8)
#define BSTRIDE 5120      // fixed slots per bucket (mean 4352, +12 sigma headroom)
#define P2CHUNK 4096      // edges per partition block
#define NBLK2  ((ETOT + P2CHUNK - 1)/P2CHUNK)   // 208
#define G1BLK  ((NNODES + 31)/32)               // 1563 gemm1 blocks

typedef __attribute__((ext_vector_type(8))) short bf8_t;   // 8 bf16 (bits in shorts)
typedef __attribute__((ext_vector_type(4))) short bf4_t;   // 4 bf16
typedef __attribute__((ext_vector_type(4))) float f4_t;
typedef __attribute__((ext_vector_type(2))) float f2_t;

constexpr float LOG2E = 1.44269504f;

constexpr size_t align256(size_t x){ return (x + 255) & ~size_t(255); }
constexpr size_t OFF_OFFSETS = 0;                                           // N ints
constexpr size_t OFF_DEG     = OFF_OFFSETS + align256((size_t)NNODES*4);    // N ints
constexpr size_t OFF_GCUR    = OFF_DEG     + align256((size_t)NNODES*4);    // NBUCK ints
constexpr size_t OFF_EPACK   = OFF_GCUR    + align256(NBUCK*4);             // NBUCK*BSTRIDE ints
constexpr size_t OFF_SRC     = OFF_EPACK   + align256((size_t)NBUCK*BSTRIDE*4);
constexpr size_t OFF_AS1     = OFF_SRC     + align256((size_t)NBUCK*BSTRIDE*4); // N*8 f32 ([node][head])
constexpr size_t OFF_AD1     = OFF_AS1     + align256((size_t)NNODES*8*4);
constexpr size_t OFF_W1T     = OFF_AD1     + align256((size_t)NNODES*8*4);  // 256*256 bf16 (n-major)
constexpr size_t OFF_W2T     = OFF_W1T     + align256(256*256*2);           // 64*256 bf16 (n-major)
constexpr size_t OFF_H1F8    = OFF_W2T     + align256(64*256*2);            // N*256 fp8 (node-major)
constexpr size_t OFF_OUT1B   = OFF_H1F8    + align256((size_t)NNODES*256);  // N*256 bf16
// h2b overlays dead h1f8 after aggregate1
constexpr size_t OFF_H2B     = OFF_H1F8;                                    // N*64 bf16
constexpr size_t OFF_AS2     = OFF_OUT1B   + align256((size_t)NNODES*256*2);
constexpr size_t OFF_AD2     = OFF_AS2     + align256((size_t)NNODES*4);

__device__ __forceinline__ unsigned short f2bf(float f){
    union { float f; unsigned u; } v; v.f = f;
    unsigned r = v.u + 0x7FFF + ((v.u >> 16) & 1);   // RNE
    return (unsigned short)(r >> 16);
}
__device__ __forceinline__ float bf2f(unsigned short s){
    union { unsigned u; float f; } v; v.u = ((unsigned)s) << 16;
    return v.f;
}

// ---------------- CSR construction: LDS multisplit, fixed-stride buckets ---

// p3 (edge partition) FUSED with gemm1: the two are data-independent
// (p3: ei/gcur -> epack; gemm1: x/w1t -> h1f8/as1/ad1), so p3's atomics
// and scatter hide under gemm1's 44 us instead of serializing in front.
// Blocks [0, NBLK2) = p3 (dispatched first -> overlap gemm1's fill);
// blocks [NBLK2, NBLK2+G1BLK) = gemm1 (R7-proven 2-barrier body).

__global__ __launch_bounds__(256) void p3_gemm1_fused(
        const int* __restrict__ ei, int* __restrict__ gcur, int* __restrict__ epack,
        const float* __restrict__ x, const short* __restrict__ w1t,
        const float* __restrict__ a1s, const float* __restrict__ a1d,
        unsigned char* __restrict__ h1f8, float* __restrict__ as1, float* __restrict__ ad1){
    __shared__ int hh[NBUCK];   // p3 hist -> block base per bucket
    __shared__ int rr[NBUCK];   // p3 intra-block rank cursor
    __shared__ short As[2][32][40];   // gemm1 A dbuf (5.1 KB)
    const int t = threadIdx.x;

    if (blockIdx.x < NBLK2){
        // ---------------- p3 body (verbatim, block id = blockIdx.x) --------
        for (int i = t; i < NBUCK; i += 256){ hh[i] = 0; rr[i] = 0; }
        __syncthreads();
        const int base = blockIdx.x * P2CHUNK;
        int srcs[P2CHUNK/256], dsts[P2CHUNK/256];
#pragma unroll
        for (int j = 0; j < P2CHUNK/256; j++){
            int e = base + j*256 + t;
            if (e < ETOT){
                if (e < EORIG){ srcs[j] = ei[e]; dsts[j] = ei[EORIG + e]; }
                else          { srcs[j] = dsts[j] = e - EORIG; }
                atomicAdd(&hh[dsts[j] >> 8], 1);
            } else dsts[j] = -1;
        }
        __syncthreads();
        for (int i = t; i < NBUCK; i += 256){
            int c = hh[i];
            hh[i] = c ? atomicAdd(&gcur[i], c) : 0;
        }
        __syncthreads();
#pragma unroll
        for (int j = 0; j < P2CHUNK/256; j++){
            if (dsts[j] >= 0){
                int b = dsts[j] >> 8;
                int rk = atomicAdd(&rr[b], 1);
                epack[hh[b] + rk] = (srcs[j] << 8) | (dsts[j] & 255);
            }
        }
        return;
    }

    // ---------------- gemm1 body (R7-exact, bid = blockIdx.x - NBLK2) -----
    const int lane = t & 63, wave = t >> 6;    // 4 waves
    const int quad = lane >> 4, l15 = lane & 15;
    const int r0 = (blockIdx.x - NBLK2) * 32;
    const int srow = t >> 3, skoff = (t & 7) * 4;   // srow 0..31, 8 thr/row x 16B
    const bool arow_ok = (r0 + srow) < NNODES;
    const float* xrow = x + (size_t)(r0 + srow)*256 + skoff;
    const short* wbase = w1t + (size_t)(wave*64 + l15)*256 + quad*8;
    f4_t zero4 = {0.f,0.f,0.f,0.f};
    f4_t acc[2][4];
#pragma unroll
    for (int i=0;i<2;i++)
#pragma unroll
      for (int j=0;j<4;j++) acc[i][j] = zero4;

    // prologue: step-0 A -> LDS buf0, step-0 B -> regs
    float4 xa = {0,0,0,0};
    if (arow_ok) xa = *(const float4*)(xrow);
    bf8_t bcur[4], bnxt[4];
#pragma unroll
    for (int j=0;j<4;j++) bcur[j] = *(const bf8_t*)(wbase + j*16*256);
    {
        bf4_t a0;
        a0[0]=f2bf(xa.x); a0[1]=f2bf(xa.y); a0[2]=f2bf(xa.z); a0[3]=f2bf(xa.w);
        *(bf4_t*)&As[0][srow][skoff] = a0;
    }
    __syncthreads();
    int cur = 0;
#pragma unroll
    for (int s = 0; s < 8; s++){
        if (s < 7){
            const int kn = s*32 + 32;
            if (arow_ok) xa = *(const float4*)(xrow + kn);
#pragma unroll
            for (int j=0;j<4;j++) bnxt[j] = *(const bf8_t*)(wbase + j*16*256 + kn);
        }
        bf8_t af[2];
#pragma unroll
        for (int i=0;i<2;i++) af[i] = *(const bf8_t*)&As[cur][i*16 + l15][quad*8];
#pragma unroll
        for (int i=0;i<2;i++)
#pragma unroll
          for (int j=0;j<4;j++)
            acc[i][j] = __builtin_amdgcn_mfma_f32_16x16x32_bf16(af[i], bcur[j], acc[i][j], 0,0,0);
        if (s < 7){
            bf4_t a0;
            a0[0]=f2bf(xa.x); a0[1]=f2bf(xa.y); a0[2]=f2bf(xa.z); a0[3]=f2bf(xa.w);
            *(bf4_t*)&As[cur^1][srow][skoff] = a0;
            __syncthreads();
            cur ^= 1;
#pragma unroll
            for (int j=0;j<4;j++) bcur[j] = bnxt[j];
        }
    }
    // epilogue: fp8 store (HW cvt, node-major) + fused alpha projections (x log2e)
    const int colbase = wave*64;             // this wave's 64 cols = 2 heads
    const int head0 = colbase >> 5;
    float cs[4], cd[4];
#pragma unroll
    for (int j=0;j<4;j++){
        cs[j] = a1s[colbase + j*16 + l15] * LOG2E;
        cd[j] = a1d[colbase + j*16 + l15] * LOG2E;
    }
#pragma unroll
    for (int i=0;i<2;i++){
        int rowb = r0 + i*16 + quad*4;
#pragma unroll
        for (int reg=0; reg<4; reg++){
            int row = rowb + reg;
            bool valid = row < NNODES;
            float sp0=0.f, dp0=0.f, sp1=0.f, dp1=0.f;
#pragma unroll
            for (int j=0;j<4;j++){
                float v = acc[i][j][reg];
                if (j < 2){ sp0 += v*cs[j]; dp0 += v*cd[j]; }
                else      { sp1 += v*cs[j]; dp1 += v*cd[j]; }
                if (valid){
                    unsigned enc = (unsigned)__builtin_amdgcn_cvt_pk_fp8_f32(v, v, 0, false);
                    h1f8[(size_t)row*256 + colbase + j*16 + l15] = (unsigned char)(enc & 0xffu);
                }
            }
            sp0 += __shfl_xor(sp0,1); sp0 += __shfl_xor(sp0,2); sp0 += __shfl_xor(sp0,4); sp0 += __shfl_xor(sp0,8);
            dp0 += __shfl_xor(dp0,1); dp0 += __shfl_xor(dp0,2); dp0 += __shfl_xor(dp0,4); dp0 += __shfl_xor(dp0,8);
            sp1 += __shfl_xor(sp1,1); sp1 += __shfl_xor(sp1,2); sp1 += __shfl_xor(sp1,4); sp1 += __shfl_xor(sp1,8);
            dp1 += __shfl_xor(dp1,1); dp1 += __shfl_xor(dp1,2); dp1 += __shfl_xor(dp1,4); dp1 += __shfl_xor(dp1,8);
            if (valid && l15 == 0){
                as1[row*8 + head0    ] = sp0;
                ad1[row*8 + head0    ] = dp0;
                as1[row*8 + head0 + 1] = sp1;
                ad1[row*8 + head0 + 1] = dp1;
            }
        }
    }
}

// one block per bucket -> local CSR in LDS; offsets/deg coalesced;
// srclist writes confined to the bucket's contiguous region.
__global__ __launch_bounds__(256) void p4_csr(const int* __restrict__ gcur, const int* __restrict__ epack,
                                              int* __restrict__ offsets, int* __restrict__ deg_g,
                                              int* __restrict__ srclist){
    __shared__ int deg[256];
    __shared__ int sm[256];
    __shared__ int cur[256];
    const int b = blockIdx.x, t = threadIdx.x;
    const int s0 = b * BSTRIDE, s1 = gcur[b];
    deg[t] = 0; __syncthreads();
    for (int i = s0 + t; i < s1; i += 256) atomicAdd(&deg[epack[i] & 255], 1);
    __syncthreads();
    int v = deg[t];
    sm[t] = v; __syncthreads();
    for (int off = 1; off < 256; off <<= 1){
        int add = (t >= off) ? sm[t-off] : 0;
        __syncthreads();
        sm[t] += add;
        __syncthreads();
    }
    int excl = sm[t] - v;
    int node = (b << 8) + t;
    if (node < NNODES){ offsets[node] = s0 + excl; deg_g[node] = v; }
    cur[t] = s0 + excl;
    __syncthreads();
    for (int i = s0 + t; i < s1; i += 256){
        int p = epack[i];
        int pos = atomicAdd(&cur[p & 255], 1);
        srclist[pos] = p >> 8;
    }
}

// ---------------- weight transpose+convert + gcur init (one launch) --------

__global__ __launch_bounds__(256) void conv_w_k(const float* __restrict__ W1, const float* __restrict__ W2,
                                                short* __restrict__ w1t, short* __restrict__ w2t,
                                                int* __restrict__ gcur){
    int o = blockIdx.x*256 + threadIdx.x;
    if (o < NBUCK) gcur[o] = o * BSTRIDE;
    if (o < 256*256){
        int n = o >> 8, k = o & 255;
        w1t[o] = (short)f2bf(W1[k*256 + n]);
    } else {
        int o2 = o - 256*256;
        if (o2 < 64*256){
            int n = o2 >> 8, k = o2 & 255;
            w2t[o2] = (short)f2bf(W2[k*64 + n]);
        }
    }
}

// ---------------- GEMM2 (MFMA): h2b = bf16(out1b @ W2), fused as2/ad2 ------
// (round-0 proven version: 128-row tile, 256 threads, LDS-staged A and B)

__global__ __launch_bounds__(256) void gemm2_mfma(const short* __restrict__ ab, const short* __restrict__ w2t,
        const float* __restrict__ a2s, const float* __restrict__ a2d,
        short* __restrict__ h2b, float* __restrict__ as2, float* __restrict__ ad2){
    __shared__ short As[128][40];
    __shared__ short Bs[64][40];
    const int t = threadIdx.x;
    const int lane = t & 63, wave = t >> 6;
    const int quad = lane >> 4, l15 = lane & 15;
    const int r0 = blockIdx.x * 128;
    const int srow = t >> 2, skoff = (t & 3) * 8;
    f4_t zero4 = {0.f,0.f,0.f,0.f};
    f4_t acc[2][4];
#pragma unroll
    for (int i=0;i<2;i++)
#pragma unroll
      for (int j=0;j<4;j++) acc[i][j] = zero4;

    for (int kk = 0; kk < 256; kk += 32){
        bf8_t a0 = {}, a1v = {};
        if (r0 + srow < NNODES)      a0  = *(const bf8_t*)(ab + (size_t)(r0+srow)*256 + kk + skoff);
        if (r0 + srow + 64 < NNODES) a1v = *(const bf8_t*)(ab + (size_t)(r0+srow+64)*256 + kk + skoff);
        bf8_t b0 = *(const bf8_t*)(w2t + (size_t)srow*256 + kk + skoff);   // srow = n (0..63)
        __syncthreads();
        *(bf8_t*)&As[srow   ][skoff] = a0;
        *(bf8_t*)&As[srow+64][skoff] = a1v;
        *(bf8_t*)&Bs[srow   ][skoff] = b0;
        __syncthreads();
        bf8_t af[2], bfr[4];
#pragma unroll
        for (int i=0;i<2;i++) af[i]  = *(const bf8_t*)&As[wave*32 + i*16 + l15][quad*8];
#pragma unroll
        for (int j=0;j<4;j++) bfr[j] = *(const bf8_t*)&Bs[j*16 + l15][quad*8];
#pragma unroll
        for (int i=0;i<2;i++)
#pragma unroll
          for (int j=0;j<4;j++)
            acc[i][j] = __builtin_amdgcn_mfma_f32_16x16x32_bf16(af[i], bfr[j], acc[i][j], 0,0,0);
    }
    float cs[4], cd[4];
#pragma unroll
    for (int j=0;j<4;j++){
        cs[j] = a2s[j*16 + l15] * LOG2E;
        cd[j] = a2d[j*16 + l15] * LOG2E;
    }
#pragma unroll
    for (int i=0;i<2;i++){
        int rowb = r0 + wave*32 + i*16 + quad*4;
#pragma unroll
        for (int reg=0; reg<4; reg++){
            int row = rowb + reg;
            bool valid = row < NNODES;
            float sp=0.f, dp=0.f;
#pragma unroll
            for (int j=0;j<4;j++){
                float v = acc[i][j][reg];
                sp += v*cs[j]; dp += v*cd[j];
                if (valid) h2b[(size_t)row*64 + j*16 + l15] = (short)f2bf(v);
            }
            sp += __shfl_xor(sp,1); sp += __shfl_xor(sp,2); sp += __shfl_xor(sp,4); sp += __shfl_xor(sp,8);
            dp += __shfl_xor(dp,1); dp += __shfl_xor(dp,2); dp += __shfl_xor(dp,4); dp += __shfl_xor(dp,8);
            if (valid && l15 == 0){ as2[row] = sp; ad2[row] = dp; }
        }
    }
}

// ---------------- attention aggregation 1: R0 structure + 2-deep pipeline --
// Per 8-edge group: prefetch group g+1's eight 4B row-slices into registers
// BEFORE accumulating group g, so the serial 8-FMA accumulation chain and
// the p-compute overlap the next group's L2/L3 gather latency (2x MLP).
// Accumulation order per edge unchanged -> bit-identical numerics.

__global__ __launch_bounds__(256) void aggregate1_k(const unsigned char* __restrict__ h1f8,
        const float* __restrict__ as1, const float* __restrict__ ad1,
        const int* __restrict__ offsets, const int* __restrict__ deg_g,
        const int* __restrict__ srclist,
        const float* __restrict__ b1, short* __restrict__ out1b){
    int d = blockIdx.x*4 + (threadIdx.x >> 6);
    int lane = threadIdx.x & 63;
    if (d >= NNODES) return;
    const int head_g = lane >> 3;    // gather phase: lane covers channels head_g*32 + (lane&7)*4 ..
    const int head_p = lane & 7;     // p phase: lane computes p(edge = lane>>3, head = lane&7)
    const int ep     = lane >> 3;
    int start = offsets[d];
    int deg = deg_g[d];
    float ad_p = ad1[d*8 + head_p];
    float denom = 0.f;
    f2_t acc01 = {0.f,0.f}, acc23 = {0.f,0.f};
    for (int w = 0; w < deg; w += 64){
        int deg_w = min(64, deg - w);
        int s_reg = srclist[start + w + min(lane, deg_w-1)];
        int ngr = (deg_w + 7) >> 3;
        // p for group g: edges g*8 .. g*8+7 of this window, all 8 heads
        auto comp_p = [&](int g)->float{
            int ei = g*8 + ep;
            int s  = __shfl(s_reg, min(ei, deg_w-1));
            float e = as1[s*8 + head_p] + ad_p;
            e = fmaxf(0.2f*e, e);
            float p = exp2f(e);
            return (ei < deg_w) ? p : 0.f;
        };
        // gather group g's rows (this lane's 4 channels of each of 8 edges)
        auto fetch = [&](int g, unsigned wv[8]){
#pragma unroll
            for (int e = 0; e < 8; e++){
                int se = __shfl(s_reg, g*8 + e);
                wv[e] = *(const unsigned*)(h1f8 + (size_t)se*256 + lane*4);
            }
        };
        float p_reg = comp_p(0);
        unsigned wv[8];
        fetch(0, wv);
        for (int g = 0; g < ngr; g++){
            float p_cur = p_reg;
            unsigned wn[8];
            if (g + 1 < ngr){
                p_reg = comp_p(g+1);
                fetch(g+1, wn);          // next group's gathers in flight
            }
#pragma unroll
            for (int e = 0; e < 8; e++){
                float pe = __shfl(p_cur, e*8 + head_g);
                f2_t lo = __builtin_amdgcn_cvt_pk_f32_fp8(wv[e], false);
                f2_t hi = __builtin_amdgcn_cvt_pk_f32_fp8(wv[e], true);
                acc01 += pe*lo;
                acc23 += pe*hi;
                denom += pe;
            }
            if (g + 1 < ngr){
#pragma unroll
                for (int e = 0; e < 8; e++) wv[e] = wn[e];
            }
        }
    }
    float inv = 1.f / denom;
    float4 bv = *(const float4*)(b1 + lane*4);
    ushort4 us;
    us.x = f2bf(fmaxf(acc01[0]*inv + bv.x, 0.f));
    us.y = f2bf(fmaxf(acc01[1]*inv + bv.y, 0.f));
    us.z = f2bf(fmaxf(acc23[0]*inv + bv.z, 0.f));
    us.w = f2bf(fmaxf(acc23[1]*inv + bv.w, 0.f));
    *(ushort4*)(out1b + (size_t)d*256 + lane*4) = us;
}

// ---------------- attention aggregation 2: + 2-deep gather pipeline --------
// Same transform as agg1: per 8-edge group, prefetch group g+1's dwordx4
// gather (and its pe/se shuffles) before accumulating group g, overlapping
// the serial 64-FMA accumulation with the next gather's L2/L3 latency.
// Per-edge accumulation order unchanged -> bit-identical numerics.

__global__ __launch_bounds__(256) void aggregate2_k(const unsigned short* __restrict__ h2b,
        const float* __restrict__ as2, const float* __restrict__ ad2,
        const int* __restrict__ offsets, const int* __restrict__ deg_g,
        const int* __restrict__ srclist,
        const float* __restrict__ b2, float* __restrict__ out){
    int d = blockIdx.x*4 + (threadIdx.x >> 6);
    int lane = threadIdx.x & 63;
    if (d >= NNODES) return;
    const int sub = lane >> 3;   // edge slot (0..7)
    const int c8  = lane & 7;    // channels c8*8 .. +7
    int start = offsets[d];
    int deg = deg_g[d];
    float ad_v = ad2[d];
    float denom = 0.f;
    float accv[8] = {0.f,0.f,0.f,0.f,0.f,0.f,0.f,0.f};
    for (int w = 0; w < deg; w += 64){
        int deg_w = min(64, deg - w);
        int s_reg = srclist[start + w + min(lane, deg_w-1)];
        float ev = as2[s_reg] + ad_v;
        ev = fmaxf(0.2f*ev, ev);
        float p_lane = (lane < deg_w) ? exp2f(ev) : 0.f;
        int ngr = (deg_w + 7) >> 3;
        auto fetch = [&](int g, float &pe, bf8_t &hv){
            int eq = g*8 + sub;
            pe = __shfl(p_lane, eq);
            int se = __shfl(s_reg, eq);
            hv = *(const bf8_t*)(h2b + (size_t)se*64 + c8*8);
        };
        float pe_c; bf8_t hv_c;
        fetch(0, pe_c, hv_c);
        for (int g = 0; g < ngr; g++){
            float pe = pe_c; bf8_t hv = hv_c;
            if (g + 1 < ngr) fetch(g+1, pe_c, hv_c);   // next gather in flight
#pragma unroll
            for (int k=0;k<8;k++) accv[k] += pe * bf2f((unsigned short)hv[k]);
            denom += pe;
        }
    }
    // combine the 8 edge-subsets (lane bits 3,4,5)
#pragma unroll
    for (int k=0;k<8;k++){
        accv[k] += __shfl_xor(accv[k], 8);
        accv[k] += __shfl_xor(accv[k], 16);
        accv[k] += __shfl_xor(accv[k], 32);
    }
    denom += __shfl_xor(denom, 8);
    denom += __shfl_xor(denom, 16);
    denom += __shfl_xor(denom, 32);
    float inv = 1.f / denom;
    float v[8];
    float mx = -1e30f;
#pragma unroll
    for (int k=0;k<8;k++){
        v[k] = accv[k]*inv + b2[c8*8 + k];
        mx = fmaxf(mx, v[k]);
    }
    mx = fmaxf(mx, __shfl_xor(mx, 1));
    mx = fmaxf(mx, __shfl_xor(mx, 2));
    mx = fmaxf(mx, __shfl_xor(mx, 4));
    float ss = 0.f;
#pragma unroll
    for (int k=0;k<8;k++) ss += __expf(v[k] - mx);
    ss += __shfl_xor(ss, 1);
    ss += __shfl_xor(ss, 2);
    ss += __shfl_xor(ss, 4);
    if (sub == 0){
        float lg = mx + __logf(ss);
        float4 o0 = {v[0]-lg, v[1]-lg, v[2]-lg, v[3]-lg};
        float4 o1 = {v[4]-lg, v[5]-lg, v[6]-lg, v[7]-lg};
        *(float4*)(out + (size_t)d*64 + c8*8)     = o0;
        *(float4*)(out + (size_t)d*64 + c8*8 + 4) = o1;
    }
}

// ---------------- launch ----------------

extern "C" void kernel_launch(void* const* d_in, const int* in_sizes, int n_in,
                              void* d_out, int out_size, void* d_ws, size_t ws_size,
                              hipStream_t stream){
    const float* x      = (const float*)d_in[0];
    const int*   ei     = (const int*)  d_in[1];
    const float* W1     = (const float*)d_in[2];
    const float* a_src1 = (const float*)d_in[3];
    const float* a_dst1 = (const float*)d_in[4];
    const float* b1     = (const float*)d_in[5];
    const float* W2     = (const float*)d_in[6];
    const float* a_src2 = (const float*)d_in[7];
    const float* a_dst2 = (const float*)d_in[8];
    const float* b2     = (const float*)d_in[9];

    char* ws = (char*)d_ws;
    int*   offsets = (int*)  (ws + OFF_OFFSETS);
    int*   deg_g   = (int*)  (ws + OFF_DEG);
    int*   gcur    = (int*)  (ws + OFF_GCUR);
    int*   epack   = (int*)  (ws + OFF_EPACK);
    int*   srclist = (int*)  (ws + OFF_SRC);
    float* as1     = (float*)(ws + OFF_AS1);
    float* ad1     = (float*)(ws + OFF_AD1);
    short* w1t     = (short*)(ws + OFF_W1T);
    short* w2t     = (short*)(ws + OFF_W2T);
    unsigned char* h1f8 = (unsigned char*)(ws + OFF_H1F8);
    short* out1b   = (short*)(ws + OFF_OUT1B);
    short* h2b     = (short*)(ws + OFF_H2B);
    float* as2     = (float*)(ws + OFF_AS2);
    float* ad2     = (float*)(ws + OFF_AD2);

    // weight prep + gcur init (must precede the fused p3|gemm1)
    conv_w_k<<<(256*256 + 64*256 + 255)/256, 256, 0, stream>>>(W1, W2, w1t, w2t, gcur);

    // fused: p3 edge-partition (blocks 0..NBLK2-1) || gemm1 (rest)
    p3_gemm1_fused<<<NBLK2 + G1BLK, 256, 0, stream>>>(ei, gcur, epack,
        x, w1t, a_src1, a_dst1, h1f8, as1, ad1);

    // CSR finalize
    p4_csr<<<NBUCK, 256, 0, stream>>>(gcur, epack, offsets, deg_g, srclist);

    // Layer 1 aggregation
    aggregate1_k<<<(NNODES+3)/4, 256, 0, stream>>>(h1f8, as1, ad1, offsets, deg_g, srclist, b1, out1b);

    // Layer 2
    gemm2_mfma<<<(NNODES+127)/128, 256, 0, stream>>>(out1b, w2t, a_src2, a_dst2, h2b, as2, ad2);
    aggregate2_k<<<(NNODES+3)/4, 256, 0, stream>>>((const unsigned short*)h2b, as2, ad2, offsets, deg_g, srclist, b2, (float*)d_out);
}